// Round 1
// 1691.869 us; speedup vs baseline: 1.1220x; 1.1220x over previous
//
#include <hip/hip_runtime.h>

typedef unsigned short u16;
typedef float f32x4 __attribute__((ext_vector_type(4)));
typedef int   i32x4 __attribute__((ext_vector_type(4)));
typedef short bf16x8 __attribute__((ext_vector_type(8)));

#define CCH    192
#define HW     16384
#define NPIX   131072          // B*H*W
#define NELEM  25165824        // NPIX*CCH
#define NSAMP  3145728         // CCH*HW (per-sample GroupNorm count)

__device__ __forceinline__ float b2f(u16 u) {
  return __uint_as_float(((unsigned)u) << 16);
}
__device__ __forceinline__ u16 f2b(float f) {
  unsigned u = __float_as_uint(f);
  unsigned r = (u + 0x7fffu + ((u >> 16) & 1u)) >> 16;   // RNE
  return (u16)r;
}
__device__ __forceinline__ void unpack8(i32x4 v, float* f) {
#pragma unroll
  for (int i = 0; i < 4; i++) {
    unsigned u = (unsigned)v[i];
    f[2 * i]     = __uint_as_float(u << 16);
    f[2 * i + 1] = __uint_as_float(u & 0xffff0000u);
  }
}
__device__ __forceinline__ i32x4 pack8(const float* f) {
  i32x4 r;
#pragma unroll
  for (int i = 0; i < 4; i++) {
    unsigned lo = f2b(f[2 * i]);
    unsigned hi = f2b(f[2 * i + 1]);
    r[i] = (int)(lo | (hi << 16));
  }
  return r;
}

// ---------------------------------------------------------------- stats ----
// fp32 NCHW input; per-sample sum / sumsq via atomics.
__global__ __launch_bounds__(256) void stats_partial(
    const float* __restrict__ A, const float* __restrict__ B,
    float* __restrict__ acc, int slotbase) {
  const float* src = (blockIdx.z == 0) ? A : B;
  int sample = blockIdx.y;
  size_t base = (size_t)sample * NSAMP + (size_t)blockIdx.x * 32768;
  float s = 0.f, q = 0.f;
  for (int it = 0; it < 16; it++) {
    const float* ptr = src + base + it * 2048 + threadIdx.x * 8;
    f32x4 v0 = *(const f32x4*)ptr;
    f32x4 v1 = *(const f32x4*)(ptr + 4);
#pragma unroll
    for (int i = 0; i < 4; i++) {
      s += v0[i] + v1[i];
      q += v0[i] * v0[i] + v1[i] * v1[i];
    }
  }
#pragma unroll
  for (int o = 32; o > 0; o >>= 1) {
    s += __shfl_down(s, o);
    q += __shfl_down(q, o);
  }
  __shared__ float red[8];
  int wv = threadIdx.x >> 6;
  if ((threadIdx.x & 63) == 0) { red[wv * 2] = s; red[wv * 2 + 1] = q; }
  __syncthreads();
  if (threadIdx.x == 0) {
    float S = red[0] + red[2] + red[4] + red[6];
    float Q = red[1] + red[3] + red[5] + red[7];
    int e = ((slotbase + blockIdx.z) * 8 + sample) * 2;
    atomicAdd(&acc[e], S);
    atomicAdd(&acc[e + 1], Q);
  }
}

__global__ void finalize_stats(const float* __restrict__ acc,
                               float* __restrict__ mr, int entbase, int nent) {
  int i = threadIdx.x;
  if (i < nent) {
    int e = entbase + i;
    float s = acc[e * 2], q = acc[e * 2 + 1];
    const float invN = 1.0f / (float)NSAMP;
    float mean = s * invN;
    float var = q * invN - mean * mean;
    mr[e * 2] = mean;
    mr[e * 2 + 1] = rsqrtf(var + 1e-5f);
  }
}

// ------------------------------- groupnorm + NCHW(fp32) -> NHWC(bf16) ------
__global__ __launch_bounds__(256) void norm_t(
    const float* __restrict__ in, u16* __restrict__ outp,
    const float* __restrict__ g, const float* __restrict__ bb,
    const float* __restrict__ mr, int slot) {
  __shared__ u16 tile[128 * 201];   // [x][c], stride 201 to break conflicts
  int yy = blockIdx.x, b = blockIdx.y;
  int e = (slot * 8 + b) * 2;
  float mean = mr[e], rstd = mr[e + 1];
  int tid = threadIdx.x;
  for (int task = tid; task < 3072; task += 256) {   // 192 c x 16 xchunks
    int c = task >> 4, xc = task & 15;
    const float* p = in + (size_t)(b * CCH + c) * HW + yy * 128 + xc * 8;
    f32x4 v0 = *(const f32x4*)p;
    f32x4 v1 = *(const f32x4*)(p + 4);
    float sc = rstd * g[c];
    float of = bb[c] - mean * sc;
#pragma unroll
    for (int i = 0; i < 4; i++) {
      tile[(xc * 8 + i) * 201 + c]       = f2b(v0[i] * sc + of);
      tile[(xc * 8 + 4 + i) * 201 + c]   = f2b(v1[i] * sc + of);
    }
  }
  __syncthreads();
  size_t ob = ((size_t)b * HW + (size_t)yy * 128) * CCH;
  for (int task = tid; task < 3072; task += 256) {   // 128 x x 24 cchunks
    int xx = task / 24, cc = task % 24;
    i32x4 v;
#pragma unroll
    for (int i = 0; i < 4; i++) {
      unsigned lo = tile[xx * 201 + cc * 8 + 2 * i];
      unsigned hi = tile[xx * 201 + cc * 8 + 2 * i + 1];
      v[i] = (int)(lo | (hi << 16));
    }
    *(i32x4*)(outp + ob + (size_t)xx * CCH + cc * 8) = v;
  }
}

// ----------------------------------------------------- bias rearrangement --
// Pre-gather rel-pos bias into MFMA C/D-layout order: [h][mi][nj][lane][r]
// so the attention epilogue reads it as coalesced f32x4 (L2-resident, 64KB).
__global__ void build_bias(const float* __restrict__ relb,
                           float* __restrict__ biasx) {
  int tid = threadIdx.x;
  for (int i = tid; i < 16384; i += 256) {
    int r    = i & 3;
    int lane = (i >> 2) & 63;
    int nj   = (i >> 8) & 3;
    int mi   = (i >> 10) & 3;
    int h    = (i >> 12) & 3;
    int q = 16 * mi + (lane >> 4) * 4 + r;   // query token
    int k = 16 * nj + (lane & 15);           // key token
    int qy = q >> 3, qx = q & 7, ky = k >> 3, kx = k & 7;
    biasx[i] = relb[h * 225 + (qy - ky + 7) * 15 + (qx - kx + 7)];
  }
}

// ------------------------------------------------------------ attention ----
// MFMA version. One block per window; wave h = head h.
// Fragment layouts mirror gemm_kernel (verified): A row=lane&15, k=(lane>>4)*8+i
// C/D: col=lane&15, row=(lane>>4)*4+reg.
// K staged [tok][72] with ch 48..63 zero-padded (so K=48 runs as 2 x K32;
// Q's out-of-head channels 48..63 read finite garbage * 0 = 0).
// V staged transposed [ch][72-stride tok] (lane=token staging -> LDS
// column writes hit all 32 banks).
// P (bf16 exp values) overwrites K buffer (wave-private; K dead after QK^T),
// O overwrites it again, then a cooperative coalesced gather stores NHWC bf16.
__global__ __launch_bounds__(256) void attn_kernel(
    const u16* __restrict__ qkv, const float* __restrict__ biasx,
    u16* __restrict__ outp) {
  __shared__ u16 kp[4][64 * 72];   // K padded; then P; then O
  __shared__ u16 vt[4][48 * 72];   // V^T [ch][tok]
  int tid = threadIdx.x;
  int h = tid >> 6, lane = tid & 63;
  int l15 = lane & 15, g4 = lane >> 4;
  int win = blockIdx.x;
  int b = win >> 8, wy = (win >> 4) & 15, wx = win & 15;
  int pbase = (b << 14) + (wy * 8) * 128 + wx * 8;

  // ---- stage K: task = tok*24 + hh*6 + c (coalesced 16B global reads)
  for (int task = tid; task < 1536; task += 256) {
    int tok = task / 24;
    int r24 = task - tok * 24;
    int hh = r24 / 6;
    int c = r24 - hh * 6;
    int p = pbase + (tok >> 3) * 128 + (tok & 7);
    i32x4 v = *(const i32x4*)(qkv + (size_t)p * 576 + 192 + hh * 48 + c * 8);
    *(i32x4*)&kp[hh][tok * 72 + c * 8] = v;
  }
  // zero-pad channels 48..63
  {
    i32x4 z = {0, 0, 0, 0};
    for (int task = tid; task < 512; task += 256) {
      int hh = task >> 7, rem = task & 127, tok = rem >> 1, c = rem & 1;
      *(i32x4*)&kp[hh][tok * 72 + 48 + c * 8] = z;
    }
  }
  // ---- stage V^T: task = chidx*64 + tok (conflict-free LDS writes)
  for (int task = tid; task < 1536; task += 256) {
    int chidx = task >> 6, tok = task & 63;
    int hh = chidx / 6, c = chidx - hh * 6;
    int p = pbase + (tok >> 3) * 128 + (tok & 7);
    i32x4 v = *(const i32x4*)(qkv + (size_t)p * 576 + 384 + hh * 48 + c * 8);
#pragma unroll
    for (int i = 0; i < 4; i++) {
      unsigned u = (unsigned)v[i];
      vt[hh][(c * 8 + 2 * i) * 72 + tok]     = (u16)(u & 0xffffu);
      vt[hh][(c * 8 + 2 * i + 1) * 72 + tok] = (u16)(u >> 16);
    }
  }
  __syncthreads();

  // ---- QK^T: S[64][64], 4x4 tiles of 16x16, K=64 (padded) as 2 k-steps
  int ptok[4];
#pragma unroll
  for (int mi = 0; mi < 4; mi++) {
    int t = 16 * mi + l15;
    ptok[mi] = pbase + (t >> 3) * 128 + (t & 7);
  }
  f32x4 acc[4][4];
#pragma unroll
  for (int i = 0; i < 4; i++)
#pragma unroll
    for (int j = 0; j < 4; j++) {
      f32x4 z = {0.f, 0.f, 0.f, 0.f};
      acc[i][j] = z;
    }
#pragma unroll
  for (int s = 0; s < 2; s++) {
    bf16x8 qf[4], kf[4];
#pragma unroll
    for (int mi = 0; mi < 4; mi++)
      qf[mi] = *(const bf16x8*)(qkv + (size_t)ptok[mi] * 576 + h * 48 + s * 32 + g4 * 8);
#pragma unroll
    for (int nj = 0; nj < 4; nj++)
      kf[nj] = *(const bf16x8*)&kp[h][(16 * nj + l15) * 72 + s * 32 + g4 * 8];
#pragma unroll
    for (int mi = 0; mi < 4; mi++)
#pragma unroll
      for (int nj = 0; nj < 4; nj++)
        acc[mi][nj] = __builtin_amdgcn_mfma_f32_16x16x32_bf16(qf[mi], kf[nj], acc[mi][nj], 0, 0, 0);
  }

  // ---- softmax (row sums; normalization deferred to O epilogue)
  const float scale = 0.14433756729740643f;   // 48^-0.5
  float sums[4][4];
#pragma unroll
  for (int mi = 0; mi < 4; mi++) {
#pragma unroll
    for (int r = 0; r < 4; r++) sums[mi][r] = 0.f;
#pragma unroll
    for (int nj = 0; nj < 4; nj++) {
      f32x4 bv = *(const f32x4*)&biasx[(((h * 4 + mi) * 4 + nj) * 64 + lane) * 4];
#pragma unroll
      for (int r = 0; r < 4; r++) {
        float sv = acc[mi][nj][r] * scale + bv[r];
        sv = fminf(fmaxf(sv, -60.f), 60.f);
        float e = __expf(sv);
        acc[mi][nj][r] = e;
        sums[mi][r] += e;
      }
    }
  }
#pragma unroll
  for (int mi = 0; mi < 4; mi++)
#pragma unroll
    for (int r = 0; r < 4; r++) {
      float s = sums[mi][r];
      s += __shfl_xor(s, 1);
      s += __shfl_xor(s, 2);
      s += __shfl_xor(s, 4);
      s += __shfl_xor(s, 8);
      sums[mi][r] = 1.0f / s;
    }
  // write P (bf16) over K buffer: row=query, col=key
#pragma unroll
  for (int mi = 0; mi < 4; mi++)
#pragma unroll
    for (int nj = 0; nj < 4; nj++)
#pragma unroll
      for (int r = 0; r < 4; r++)
        kp[h][(16 * mi + g4 * 4 + r) * 72 + 16 * nj + l15] = f2b(acc[mi][nj][r]);

  // ---- PV: O[64][48], 4x3 tiles, K=64 keys as 2 k-steps
  f32x4 oacc[4][3];
#pragma unroll
  for (int i = 0; i < 4; i++)
#pragma unroll
    for (int j = 0; j < 3; j++) {
      f32x4 z = {0.f, 0.f, 0.f, 0.f};
      oacc[i][j] = z;
    }
#pragma unroll
  for (int s = 0; s < 2; s++) {
    bf16x8 pf[4], vf[3];
#pragma unroll
    for (int mi = 0; mi < 4; mi++)
      pf[mi] = *(const bf16x8*)&kp[h][(16 * mi + l15) * 72 + s * 32 + g4 * 8];
#pragma unroll
    for (int n = 0; n < 3; n++)
      vf[n] = *(const bf16x8*)&vt[h][(16 * n + l15) * 72 + s * 32 + g4 * 8];
#pragma unroll
    for (int mi = 0; mi < 4; mi++)
#pragma unroll
      for (int n = 0; n < 3; n++)
        oacc[mi][n] = __builtin_amdgcn_mfma_f32_16x16x32_bf16(pf[mi], vf[n], oacc[mi][n], 0, 0, 0);
  }

  // ---- O epilogue: normalize, write bf16 into kp[h] as [tok][48]
#pragma unroll
  for (int mi = 0; mi < 4; mi++)
#pragma unroll
    for (int n = 0; n < 3; n++)
#pragma unroll
      for (int r = 0; r < 4; r++)
        kp[h][(16 * mi + g4 * 4 + r) * 72 + 16 * n + l15] =
            f2b(oacc[mi][n][r] * sums[mi][r]);
  __syncthreads();
  // coalesced NHWC gather-store
  for (int task = tid; task < 1536; task += 256) {
    int tok = task / 24;
    int r24 = task - tok * 24;
    int hh = r24 / 6;
    int c = r24 - hh * 6;
    int p = pbase + (tok >> 3) * 128 + (tok & 7);
    *(i32x4*)(outp + (size_t)p * 192 + hh * 48 + c * 8) =
        *(const i32x4*)&kp[hh][tok * 72 + c * 8];
  }
}

// ----------------------------------------------------------------- GEMM ----
// C[p,o] = sum_k X[p,k]*W[o,k]
// X: internal bf16 NHWC [P][K].  W: fp32 row-major [O][K] (converted to bf16
// in staging).  bias fp32.
// GM_BIAS: out bf16 [P][O]            (qkv)
// GM_GATE: out bf16 = aux(bf16) + scale*sigmoid(y)   (cross-gating)
// GM_GELU: out bf16 = gelu(y)         (ffn1)
// GM_RES : out fp32 NCHW = aux(fp32 NCHW) + y + bias (proj/ffn2 residual)
enum { GM_BIAS = 0, GM_GATE = 1, GM_GELU = 2, GM_RES = 3 };

struct SmemGemm {
  union {
    struct { u16 xs[64 * 72]; u16 ws[64 * 72]; } s;   // staged tiles, pad 72
    float y[64 * 72];                                 // epilogue repack tile
  };
};

template <int MODE>
__global__ __launch_bounds__(256) void gemm_kernel(
    const u16* __restrict__ X, const float* __restrict__ W,
    const float* __restrict__ bias, const void* aux,
    void* outv, const float* __restrict__ scale_ptr, int K, int O) {
  __shared__ SmemGemm sm;
  int tid = threadIdx.x;
  int p0 = blockIdx.x * 64;
  int o0 = blockIdx.y * 64;
  int lane = tid & 63, wave = tid >> 6;
  int l15 = lane & 15, q8 = lane >> 4;
  int wm = (wave & 1) * 32, wn = (wave >> 1) * 32;

  f32x4 acc[2][2];
#pragma unroll
  for (int i = 0; i < 2; i++)
#pragma unroll
    for (int j = 0; j < 2; j++) {
      f32x4 z = {0.f, 0.f, 0.f, 0.f};
      acc[i][j] = z;
    }

  int srow = tid >> 2;            // 0..63
  int scol = (tid & 3) * 16;      // 0,16,32,48
  const u16* xg   = X + (size_t)(p0 + srow) * K + scol;
  const float* wg = W + (size_t)(o0 + srow) * K + scol;
  u16* xst = &sm.s.xs[srow * 72 + scol];
  u16* wst = &sm.s.ws[srow * 72 + scol];

  for (int k0 = 0; k0 < K; k0 += 64) {
    __syncthreads();
    i32x4 x0 = *(const i32x4*)xg;
    i32x4 x1 = *(const i32x4*)(xg + 8);
    f32x4 wv0 = *(const f32x4*)wg;
    f32x4 wv1 = *(const f32x4*)(wg + 4);
    f32x4 wv2 = *(const f32x4*)(wg + 8);
    f32x4 wv3 = *(const f32x4*)(wg + 12);
    xg += 64; wg += 64;
    float wf[16];
#pragma unroll
    for (int i = 0; i < 4; i++) {
      wf[i] = wv0[i]; wf[4 + i] = wv1[i]; wf[8 + i] = wv2[i]; wf[12 + i] = wv3[i];
    }
    *(i32x4*)xst = x0;
    *(i32x4*)(xst + 8) = x1;
    *(i32x4*)wst = pack8(wf);
    *(i32x4*)(wst + 8) = pack8(wf + 8);
    __syncthreads();
#pragma unroll
    for (int s = 0; s < 2; s++) {
      bf16x8 a0 = *(const bf16x8*)&sm.s.xs[(wm + l15) * 72 + s * 32 + q8 * 8];
      bf16x8 a1 = *(const bf16x8*)&sm.s.xs[(wm + 16 + l15) * 72 + s * 32 + q8 * 8];
      bf16x8 b0 = *(const bf16x8*)&sm.s.ws[(wn + l15) * 72 + s * 32 + q8 * 8];
      bf16x8 b1 = *(const bf16x8*)&sm.s.ws[(wn + 16 + l15) * 72 + s * 32 + q8 * 8];
      acc[0][0] = __builtin_amdgcn_mfma_f32_16x16x32_bf16(a0, b0, acc[0][0], 0, 0, 0);
      acc[0][1] = __builtin_amdgcn_mfma_f32_16x16x32_bf16(a0, b1, acc[0][1], 0, 0, 0);
      acc[1][0] = __builtin_amdgcn_mfma_f32_16x16x32_bf16(a1, b0, acc[1][0], 0, 0, 0);
      acc[1][1] = __builtin_amdgcn_mfma_f32_16x16x32_bf16(a1, b1, acc[1][1], 0, 0, 0);
    }
  }
  __syncthreads();
  // C/D layout: col(o) = lane&15, row(p) = (lane>>4)*4 + reg
#pragma unroll
  for (int mi = 0; mi < 2; mi++) {
#pragma unroll
    for (int ni = 0; ni < 2; ni++) {
      int pl = wm + mi * 16 + q8 * 4;
      int ol = wn + ni * 16 + l15;
#pragma unroll
      for (int r = 0; r < 4; r++) {
        float v = acc[mi][ni][r];
        if (MODE == GM_RES) sm.y[ol * 72 + pl + r] = v;       // [o][p]
        else                sm.y[(pl + r) * 72 + ol] = v;     // [p][o]
      }
    }
  }
  __syncthreads();
  if (MODE == GM_RES) {
    const float* auxf = (const float*)aux;
    float* outf = (float*)outv;
    int o = tid >> 2;
    int pc = (tid & 3) * 16;
    float vals[16];
#pragma unroll
    for (int i = 0; i < 16; i++) vals[i] = sm.y[o * 72 + pc + i];
    int og = o0 + o;
    int pg = p0 + pc;
    int bi = pg >> 14;
    int r = pg & (HW - 1);
    size_t idx = ((size_t)(bi * CCH + og) << 14) + r;
    float bv = bias[og];
    f32x4 res[4];
#pragma unroll
    for (int i = 0; i < 4; i++) res[i] = *(const f32x4*)(auxf + idx + i * 4);
#pragma unroll
    for (int i = 0; i < 4; i++) {
      f32x4 w;
#pragma unroll
      for (int j = 0; j < 4; j++) w[j] = res[i][j] + vals[i * 4 + j] + bv;
      *(f32x4*)(outf + idx + i * 4) = w;
    }
  } else {
    u16* outb = (u16*)outv;
    const u16* auxb = (const u16*)aux;
    int pl = tid >> 2;
    int oc = (tid & 3) * 16;
    float vals[16];
#pragma unroll
    for (int i = 0; i < 16; i++) vals[i] = sm.y[pl * 72 + oc + i];
    int og0 = o0 + oc;
    size_t rowb = (size_t)(p0 + pl) * (size_t)O + og0;
    float sc = 0.f;
    if (MODE == GM_GATE) sc = scale_ptr[0];
    float f[16];
#pragma unroll
    for (int i = 0; i < 16; i++) {
      float v = vals[i] + bias[og0 + i];
      if (MODE == GM_GATE) {
        float sg = 1.0f / (1.0f + __expf(-v));
        v = b2f(auxb[rowb + i]) + sc * sg;
      } else if (MODE == GM_GELU) {
        v = 0.5f * v * (1.0f + erff(v * 0.70710678118654752f));
      }
      f[i] = v;
    }
    *(i32x4*)(outb + rowb) = pack8(f);
    *(i32x4*)(outb + rowb + 8) = pack8(f + 8);
  }
}

// --------------------------------------------------------------- launch ----
extern "C" void kernel_launch(void* const* d_in, const int* in_sizes, int n_in,
                              void* d_out, int out_size, void* d_ws,
                              size_t ws_size, hipStream_t stream) {
  (void)in_sizes; (void)n_in; (void)out_size; (void)ws_size;
  const float* sem       = (const float*)d_in[0];
  const float* dep       = (const float*)d_in[1];
  const float* ns_g      = (const float*)d_in[2];
  const float* ns_b      = (const float*)d_in[3];
  const float* nd_g      = (const float*)d_in[4];
  const float* nd_b      = (const float*)d_in[5];
  const float* wd2s      = (const float*)d_in[6];
  const float* bd2s      = (const float*)d_in[7];
  const float* ws2d      = (const float*)d_in[8];
  const float* bs2d      = (const float*)d_in[9];
  const float* alpha     = (const float*)d_in[10];
  const float* beta      = (const float*)d_in[11];
  const float* qkv_sem_w = (const float*)d_in[12];
  const float* qkv_sem_b = (const float*)d_in[13];
  const float* out_sem_w = (const float*)d_in[14];
  const float* out_sem_b = (const float*)d_in[15];
  const float* qkv_dep_w = (const float*)d_in[16];
  const float* qkv_dep_b = (const float*)d_in[17];
  const float* out_dep_w = (const float*)d_in[18];
  const float* out_dep_b = (const float*)d_in[19];
  const float* relb      = (const float*)d_in[20];
  const float* fs_g      = (const float*)d_in[21];
  const float* fs_b      = (const float*)d_in[22];
  const float* fs_w1     = (const float*)d_in[23];
  const float* fs_b1     = (const float*)d_in[24];
  const float* fs_w2     = (const float*)d_in[25];
  const float* fs_b2     = (const float*)d_in[26];
  const float* fd_g      = (const float*)d_in[27];
  const float* fd_b      = (const float*)d_in[28];
  const float* fd_w1     = (const float*)d_in[29];
  const float* fd_b1     = (const float*)d_in[30];
  const float* fd_w2     = (const float*)d_in[31];
  const float* fd_b2     = (const float*)d_in[32];

  float* stats_acc = (float*)d_ws;                       // 64 f32
  float* mr        = (float*)((char*)d_ws + 256);        // 64 f32
  u16* R1 = (u16*)((char*)d_ws + 1024);                  // 4x 50.3MB bf16 NHWC
  u16* R2 = R1 + NELEM;
  u16* R3 = R2 + NELEM;
  u16* R4 = R3 + NELEM;
  u16* R5 = R4 + NELEM;                                  // 151MB qkv / ffn-hid
  float* outS = (float*)d_out;                           // fp32 NCHW outputs
  float* outD = outS + NELEM;
  // biasx (64KB) parks in R1: R1 (sem_n) is dead after the two GM_GATE gemms
  // and not rewritten until the FFN norm_t, which is after both attns.
  float* biasx = (float*)R1;

  hipMemsetAsync(d_ws, 0, 512, stream);
  // GroupNorm stats on raw inputs
  stats_partial<<<dim3(96, 8, 2), 256, 0, stream>>>(sem, dep, stats_acc, 0);
  finalize_stats<<<1, 64, 0, stream>>>(stats_acc, mr, 0, 16);
  norm_t<<<dim3(128, 8), 256, 0, stream>>>(sem, R1, ns_g, ns_b, mr, 0);
  norm_t<<<dim3(128, 8), 256, 0, stream>>>(dep, R2, nd_g, nd_b, mr, 1);
  // cross-gating: sem_in = semn + a*sig(conv(depn)), dep_in = depn + b*sig(conv(semn))
  gemm_kernel<GM_GATE><<<dim3(2048, 3), 256, 0, stream>>>(R2, wd2s, bd2s, R1, R3, alpha, 192, 192);
  gemm_kernel<GM_GATE><<<dim3(2048, 3), 256, 0, stream>>>(R1, ws2d, bs2d, R2, R4, beta, 192, 192);
  // rel-pos bias in MFMA layout (R1 now dead until FFN phase)
  build_bias<<<1, 256, 0, stream>>>(relb, biasx);
  // sem stream: qkv -> attn -> outproj(+residual, fp32 NCHW)
  gemm_kernel<GM_BIAS><<<dim3(2048, 9), 256, 0, stream>>>(R3, qkv_sem_w, qkv_sem_b, nullptr, R5, nullptr, 192, 576);
  attn_kernel<<<2048, 256, 0, stream>>>(R5, biasx, R2);
  gemm_kernel<GM_RES><<<dim3(2048, 3), 256, 0, stream>>>(R2, out_sem_w, out_sem_b, sem, outS, nullptr, 192, 192);
  // dep stream
  gemm_kernel<GM_BIAS><<<dim3(2048, 9), 256, 0, stream>>>(R4, qkv_dep_w, qkv_dep_b, nullptr, R5, nullptr, 192, 576);
  attn_kernel<<<2048, 256, 0, stream>>>(R5, biasx, R2);
  gemm_kernel<GM_RES><<<dim3(2048, 3), 256, 0, stream>>>(R2, out_dep_w, out_dep_b, dep, outD, nullptr, 192, 192);
  // FFN: gn -> conv1+gelu -> conv2 (+residual into d_out, fp32)
  stats_partial<<<dim3(96, 8, 2), 256, 0, stream>>>(outS, outD, stats_acc, 2);
  finalize_stats<<<1, 64, 0, stream>>>(stats_acc, mr, 16, 16);
  norm_t<<<dim3(128, 8), 256, 0, stream>>>(outS, R1, fs_g, fs_b, mr, 2);
  norm_t<<<dim3(128, 8), 256, 0, stream>>>(outD, R3, fd_g, fd_b, mr, 3);
  gemm_kernel<GM_GELU><<<dim3(2048, 6), 256, 0, stream>>>(R1, fs_w1, fs_b1, nullptr, R5, nullptr, 192, 384);
  gemm_kernel<GM_RES><<<dim3(2048, 3), 256, 0, stream>>>(R5, fs_w2, fs_b2, outS, outS, nullptr, 384, 192);
  gemm_kernel<GM_GELU><<<dim3(2048, 6), 256, 0, stream>>>(R3, fd_w1, fd_b1, nullptr, R5, nullptr, 192, 384);
  gemm_kernel<GM_RES><<<dim3(2048, 3), 256, 0, stream>>>(R5, fd_w2, fd_b2, outD, outD, nullptr, 384, 192);
}